// Round 12
// baseline (27.356 us; speedup 1.0000x reference)
//
#include <hip/hip_runtime.h>
#include <math.h>

typedef unsigned long long u64;
typedef unsigned int u32;

constexpr int NB  = 8;
constexpr int NM  = 4096;
constexpr int KNN = 16;
constexpr int WPB = 4;             // waves per block; 4 queries per wave
constexpr int QPW = 4;
constexpr int QPB = WPB * QPW;     // 16 queries per block
constexpr int BLK = WPB * 64;      // 256 threads
constexpr int GC  = 32;            // 32x32 grid, ~4 pts/cell
constexpr int NC  = GC * GC;
constexpr int CSST = NC + 1;
constexpr int SLG = 10;            // slots/lane: 160 group cap, 640 wave cap

// d_ws layout (fully rewritten every call -> poison-safe):
//   uvS float4[NB][NM] @ 0       (512 KB) cell-ordered (u, v, origidx_bits, 0)
//   cs  u32  [NB][CSST] @ 524288 ( 33 KB) cell start offsets
constexpr size_t WS_UVS = 0;
constexpr size_t WS_CS  = (size_t)NB * NM * 16;

__device__ __forceinline__ u64 shflx64(u64 v, int m) {
  unsigned lo = (unsigned)v, hi = (unsigned)(v >> 32);
  lo = __shfl_xor(lo, m, 64);
  hi = __shfl_xor(hi, m, 64);
  return ((u64)hi << 32) | lo;
}
__device__ __forceinline__ int rfl(int x) { return __builtin_amdgcn_readfirstlane(x); }
__device__ __forceinline__ int lanes_below(u64 m) {
  return (int)__builtin_amdgcn_mbcnt_hi((u32)(m >> 32),
             __builtin_amdgcn_mbcnt_lo((u32)m, 0u));
}
__device__ __forceinline__ u32 gm16(u64 m, int lane) {   // own 16-group's ballot bits
  return (u32)(m >> ((lane >> 4) << 4)) & 0xFFFFu;
}

// ---- DPP helpers (VALU pipe, no LDS). row_ror ctrls verified in R9 (passed). ----
template<int CTRL>
__device__ __forceinline__ int dppAddI(int v) {
  return v + __builtin_amdgcn_update_dpp(0, v, CTRL, 0xF, 0xF, false);
}
template<int CTRL>
__device__ __forceinline__ float dppAddF(float v) {
  int r = __builtin_amdgcn_update_dpp(0, __float_as_int(v), CTRL, 0xF, 0xF, false);
  return v + __int_as_float(r);
}
__device__ __forceinline__ int rorSum16I(int c) {      // all 16 lanes get group sum
  c = dppAddI<0x128>(c); c = dppAddI<0x124>(c);
  c = dppAddI<0x122>(c); c = dppAddI<0x121>(c);
  return c;
}
__device__ __forceinline__ float rorSum16F(float v) {
  v = dppAddF<0x128>(v); v = dppAddF<0x124>(v);
  v = dppAddF<0x122>(v); v = dppAddF<0x121>(v);
  return v;
}
// quad_perm exchanges: 0xB1 = [1,0,3,2] (xor1), 0x4E = [2,3,0,1] (xor2)
template<int CTRL>
__device__ __forceinline__ u64 dppSwap64(u64 v) {
  int lo = __builtin_amdgcn_update_dpp(0, (int)(u32)v,        CTRL, 0xF, 0xF, false);
  int hi = __builtin_amdgcn_update_dpp(0, (int)(u32)(v >> 32), CTRL, 0xF, 0xF, false);
  return ((u64)(u32)hi << 32) | (u32)lo;
}
__device__ __forceinline__ u64 exch(u64 v, int j) {    // j is compile-time (unrolled)
  if (j == 1) return dppSwap64<0xB1>(v);
  if (j == 2) return dppSwap64<0x4E>(v);
  return shflx64(v, j);
}

// ---------------- binning: counting-sort each batch's uv into 32x32 cells ----
__global__ __launch_bounds__(1024)
void bin_pts(const float* __restrict__ uv, float4* __restrict__ uvS,
             u32* __restrict__ cs) {
  __shared__ u32 cnt[NC];
  __shared__ u32 offs[NC];
  __shared__ u32 wtot[16];
  const int bb  = blockIdx.x;
  const int tid = threadIdx.x;           // 1024 threads == NC

  cnt[tid] = 0;
  __syncthreads();

  float2 c4[4];
  int cell[4];
  #pragma unroll
  for (int i = 0; i < 4; ++i) {
    const int p = tid + i * 1024;
    const float2 c = ((const float2*)(uv + (size_t)bb * NM * 2))[p];
    int cx = (int)(c.x * 32.f); cx = cx > GC - 1 ? GC - 1 : (cx < 0 ? 0 : cx);
    int cy = (int)(c.y * 32.f); cy = cy > GC - 1 ? GC - 1 : (cy < 0 ? 0 : cy);
    c4[i] = c; cell[i] = cy * GC + cx;
    atomicAdd(&cnt[cell[i]], 1u);
  }
  __syncthreads();

  {
    const int lane = tid & 63;
    u32 inc = cnt[tid];
    #pragma unroll
    for (int o = 1; o < 64; o <<= 1) {
      const u32 t = __shfl_up(inc, o, 64);
      if (lane >= o) inc += t;
    }
    offs[tid] = inc;                      // wave-inclusive
    if (lane == 63) wtot[tid >> 6] = inc;
  }
  __syncthreads();
  if (tid < 16) {
    u32 v = wtot[tid];
    #pragma unroll
    for (int o = 1; o < 16; o <<= 1) {
      const u32 t = __shfl_up(v, o, 64);
      if (tid >= o) v += t;
    }
    wtot[tid] = v;
  }
  __syncthreads();
  {
    const int w = tid >> 6;
    const u32 base = w ? wtot[w - 1] : 0u;
    const u32 excl = base + offs[tid] - cnt[tid];
    cs[bb * CSST + tid] = excl;
    offs[tid] = excl;
    if (tid == 0) cs[bb * CSST + NC] = NM;
  }
  __syncthreads();

  #pragma unroll
  for (int i = 0; i < 4; ++i) {
    const int p = tid + i * 1024;
    const u32 pos = atomicAdd(&offs[cell[i]], 1u);
    uvS[(size_t)bb * NM + pos] =
        make_float4(c4[i].x, c4[i].y, __uint_as_float((u32)p), 0.f);
  }
}

// ---------------- main: 4 queries/wave, sorted order, quadrant windows ----
__global__ __launch_bounds__(BLK)
void knn_eig(const float* __restrict__ X, const float4* __restrict__ uvS,
             const u32* __restrict__ cs, float* __restrict__ out) {
  __shared__ u64 surv[WPB][QPW * 32];        // 4 KB: 32 slots per query

  const int tid  = threadIdx.x;
  const int lane = tid & 63;
  const int sub  = lane & 15;
  const int g4   = lane >> 4;
  const int wv   = tid >> 6;
  const int bb   = blockIdx.x >> 8;          // 256 blocks per batch
  const int s    = ((blockIdx.x & 255) << 4) + (wv << 2) + g4;  // sorted slot

  const float4* uvb = uvS + (size_t)bb * NM;
  const u32* csb = cs + bb * CSST;

  const float4 qc = uvb[s];                  // query in cell-sorted order
  const float qu = qc.x, qv = qc.y;
  const u32 oq = __float_as_uint(qc.z);      // original query index
  int cxv = (int)(qu * 32.f); cxv = cxv > GC - 1 ? GC - 1 : (cxv < 0 ? 0 : cxv);
  int cyv = (int)(qv * 32.f); cyv = cyv > GC - 1 ? GC - 1 : (cyv < 0 ? 0 : cyv);
  const int sx = (qu * 32.f - (float)cxv >= 0.5f) ? 1 : 0;
  const int sy = (qv * 32.f - (float)cyv >= 0.5f) ? 1 : 0;

  float d[SLG];
  #pragma unroll
  for (int t = 0; t < SLG; ++t) d[t] = 1e30f;

  constexpr float TAU1 = 0.0017f;            // ~22 expected survivors
  constexpr float TAU2 = 0.002197265625f;    // (1.5/32)^2: 4x4 covered radius
  constexpr float TAU3 = 0.006103515625f;    // (2.5/32)^2: 6x6 covered radius
  constexpr float TAU4 = 0.019775390625f;    // (4.5/32)^2: 10x10 covered radius

  int rs0, rs1, rs2, rs3, rs4, rs5, rc0, rc1, rc2, rc3, rc4;
  int total, tsw;
  int cnt = 0;

  // ---- warm: 4x4 quadrant window, per-lane tau1 count + one DPP reduce ----
  {
    const int x0 = min(max(cxv - 2 + sx, 0), GC - 4);
    const int y0 = min(max(cyv - 2 + sy, 0), GC - 4);
    const int b = y0 * GC + x0;
    rs0 = (int)csb[b];          rc0 = (int)csb[b + 4] - rs0;
    rs1 = (int)csb[b + GC];     rc1 = rc0 + (int)csb[b + GC + 4] - rs1;
    rs2 = (int)csb[b + 2*GC];   rc2 = rc1 + (int)csb[b + 2*GC + 4] - rs2;
    rs3 = (int)csb[b + 3*GC];   total = rc2 + (int)csb[b + 3*GC + 4] - rs3;
    rc3 = total; rc4 = total; rs4 = 0; rs5 = 0;
    int ts = min((total + 15) >> 4, SLG);
    int m1 = max(ts, __shfl_xor(ts, 16, 64));
    m1 = max(m1, __shfl_xor(m1, 32, 64));
    tsw = rfl(m1);
    int cl = 0;
    #pragma unroll
    for (int t = 0; t < SLG; ++t) {
      if (t >= tsw) break;                   // wave-uniform scalar break
      const int L = t * 16 + sub;
      int addr = rs0 + L;
      addr = (L >= rc0) ? rs1 + (L - rc0) : addr;
      addr = (L >= rc1) ? rs2 + (L - rc1) : addr;
      addr = (L >= rc2) ? rs3 + (L - rc2) : addr;
      float dd = 1e30f;
      if (L < total) {
        const float4 c = uvb[addr];
        const float dx = __fsub_rn(qu, c.x);
        const float dy = __fsub_rn(qv, c.y);
        dd = __fadd_rn(__fmul_rn(dx, dx), __fmul_rn(dy, dy));
      }
      d[t] = dd;
      cl += (dd <= TAU1) ? 1 : 0;
    }
    cnt = rorSum16I(cl);
  }

  // ---- ladder: tau1 -> tau2 (= covered radius^2, exactness preserved) ----
  float hi2 = TAU1, lo = 0.f;
  if (__any(cnt < KNN)) {
    int cl = 0;
    #pragma unroll
    for (int t = 0; t < SLG; ++t) {
      if (t >= tsw) break;
      cl += (d[t] <= TAU2) ? 1 : 0;
    }
    const int c2 = rorSum16I(cl);
    if (cnt < KNN) { lo = TAU1; hi2 = TAU2; cnt = c2; }
  }

  // ---- cold1: 6x6 quadrant window, group-parallel (edges/sparse, ~10%) ----
  if (__any(cnt < KNN)) {
    const bool need = cnt < KNN;
    int ts2 = 0;
    if (need) {
      #pragma unroll
      for (int t = 0; t < SLG; ++t) d[t] = 1e30f;
      const int x0 = min(max(cxv - 3 + sx, 0), GC - 6);
      const int y0 = min(max(cyv - 3 + sy, 0), GC - 6);
      const int b = y0 * GC + x0;
      rs0 = (int)csb[b];          rc0 = (int)csb[b + 6] - rs0;
      rs1 = (int)csb[b + GC];     rc1 = rc0 + (int)csb[b + GC + 6] - rs1;
      rs2 = (int)csb[b + 2*GC];   rc2 = rc1 + (int)csb[b + 2*GC + 6] - rs2;
      rs3 = (int)csb[b + 3*GC];   rc3 = rc2 + (int)csb[b + 3*GC + 6] - rs3;
      rs4 = (int)csb[b + 4*GC];   rc4 = rc3 + (int)csb[b + 4*GC + 6] - rs4;
      rs5 = (int)csb[b + 5*GC];   total = rc4 + (int)csb[b + 5*GC + 6] - rs5;
      ts2 = min((total + 15) >> 4, SLG);
      lo = TAU2; hi2 = TAU3;
    }
    int m1 = max(ts2, __shfl_xor(ts2, 16, 64));
    m1 = max(m1, __shfl_xor(m1, 32, 64));
    const int tsw2 = rfl(m1);
    int cl = 0;
    #pragma unroll
    for (int t = 0; t < SLG; ++t) {
      if (t >= tsw2) break;
      float dd = 1e30f;
      if (need) {
        const int L = t * 16 + sub;
        int addr = rs0 + L;
        addr = (L >= rc0) ? rs1 + (L - rc0) : addr;
        addr = (L >= rc1) ? rs2 + (L - rc1) : addr;
        addr = (L >= rc2) ? rs3 + (L - rc2) : addr;
        addr = (L >= rc3) ? rs4 + (L - rc3) : addr;
        addr = (L >= rc4) ? rs5 + (L - rc4) : addr;
        if (L < total) {
          const float4 c = uvb[addr];
          const float dx = __fsub_rn(qu, c.x);
          const float dy = __fsub_rn(qv, c.y);
          dd = __fadd_rn(__fmul_rn(dx, dx), __fmul_rn(dy, dy));
        }
        d[t] = dd;
      }
      cl += (need && dd <= TAU3) ? 1 : 0;
    }
    const int c3 = rorSum16I(cl);
    if (need) cnt = c3;
    tsw = max(tsw, tsw2);
  }

  // ---- narrow threshold until survivors fit 32/query (per-group lo/hi) ----
  for (int it = 0; __any(cnt > 32) && it < 40; ++it) {
    const float mid = 0.5f * (lo + hi2);
    int cl = 0;
    #pragma unroll
    for (int t = 0; t < SLG; ++t) {
      if (t >= tsw) break;
      cl += ((cnt > 32) && (d[t] <= mid)) ? 1 : 0;
    }
    const int c = rorSum16I(cl);
    if (cnt > 32) {
      if (!(mid > lo && mid < hi2)) cnt = 32;
      else if (c >= KNN) { hi2 = mid; cnt = c; }
      else lo = mid;
    }
  }

  // ---- compact survivors, key = (dist_bits<<32) | orig_idx ----
  u64* sb = surv[wv];
  {
    int base = 0;
    #pragma unroll
    for (int t = 0; t < SLG; ++t) {
      if (t >= tsw) break;
      const bool p = d[t] <= hi2;
      const u32 mg = gm16(__ballot(p), lane);
      if (p) {
        const int pos = base + (int)__popc(mg & ((1u << sub) - 1u));
        if (pos < 32) {
          const int L = t * 16 + sub;
          int addr = rs0 + L;
          addr = (L >= rc0) ? rs1 + (L - rc0) : addr;
          addr = (L >= rc1) ? rs2 + (L - rc1) : addr;
          addr = (L >= rc2) ? rs3 + (L - rc2) : addr;
          addr = (L >= rc3) ? rs4 + (L - rc3) : addr;
          addr = (L >= rc4) ? rs5 + (L - rc4) : addr;
          const u32 oid = ((const u32*)(uvb + addr))[2];
          sb[(g4 << 5) + pos] = ((u64)__float_as_uint(d[t]) << 32) | (u64)oid;
        }
      }
      base += (int)__popc(mg);
    }
  }

  // ---- cold2: 10x10 window, full-wave serialized (corners, ~50 queries) ----
  if (__any(cnt < KNN)) {
    #pragma unroll 1
    for (int g = 0; g < QPW; ++g) {
      if (!rfl((__shfl(cnt, g << 4, 64) < KNN) ? 1 : 0)) continue;
      const float gu = __shfl(qu, g << 4, 64);
      const float gv = __shfl(qv, g << 4, 64);
      int gcx = (int)(gu * 32.f); gcx = min(max(gcx, 0), GC - 1);
      int gcy = (int)(gv * 32.f); gcy = min(max(gcy, 0), GC - 1);
      const int gsx = (gu * 32.f - (float)gcx >= 0.5f) ? 1 : 0;
      const int gsy = (gv * 32.f - (float)gcy >= 0.5f) ? 1 : 0;
      const int x0 = min(max(gcx - 5 + gsx, 0), GC - 10);
      const int y0 = min(max(gcy - 5 + gsy, 0), GC - 10);
      int rstart[10], rcum[10];
      int cum = 0;
      #pragma unroll
      for (int r = 0; r < 10; ++r) {
        const int b = (y0 + r) * GC + x0;
        rstart[r] = (int)csb[b];
        cum += (int)csb[b + 10] - rstart[r];
        rcum[r] = cum;
      }
      const int gtotal = cum;
      const int gts = rfl(min((gtotal + 63) >> 6, SLG));
      float ghi = TAU4, glo = TAU3;
      int gcnt = 0;
      #pragma unroll
      for (int t = 0; t < SLG; ++t) {
        if (t >= gts) break;
        const int L = t * 64 + lane;
        int addr = rstart[0] + L;
        #pragma unroll
        for (int r = 1; r < 10; ++r)
          addr = (L >= rcum[r - 1]) ? rstart[r] + (L - rcum[r - 1]) : addr;
        float dd = 1e30f;
        if (L < gtotal) {
          const float4 c = uvb[addr];
          const float dx = __fsub_rn(gu, c.x);
          const float dy = __fsub_rn(gv, c.y);
          dd = __fadd_rn(__fmul_rn(dx, dx), __fmul_rn(dy, dy));
        }
        d[t] = dd;                           // warm d dead after compaction
        gcnt += (int)__popcll(__ballot(dd <= ghi));
      }
      for (int it = 0; rfl(gcnt) > 32 && it < 40; ++it) {
        const float mid = 0.5f * (glo + ghi);
        if (!(mid > glo && mid < ghi)) break;
        int c = 0;
        #pragma unroll
        for (int t = 0; t < SLG; ++t) {
          if (t >= gts) break;
          c += (int)__popcll(__ballot(d[t] <= mid));
        }
        if (c >= KNN) { ghi = mid; gcnt = c; } else glo = mid;
      }
      int base = 0;
      #pragma unroll
      for (int t = 0; t < SLG; ++t) {
        if (t >= gts) break;
        const bool p = d[t] <= ghi;
        const u64 m = __ballot(p);
        if (p) {
          const int pos = base + lanes_below(m);
          if (pos < 32) {
            const int L = t * 64 + lane;
            int addr = rstart[0] + L;
            #pragma unroll
            for (int r = 1; r < 10; ++r)
              addr = (L >= rcum[r - 1]) ? rstart[r] + (L - rcum[r - 1]) : addr;
            const u32 oid = ((const u32*)(uvb + addr))[2];
            sb[(g << 5) + pos] = ((u64)__float_as_uint(d[t]) << 32) | (u64)oid;
          }
        }
        base += (int)__popcll(m);
      }
      if (g4 == g) cnt = min(rfl(gcnt), 32);
    }
  }

  // ---- top-16 selection: sort v0 asc, v1 desc (parallel chains), min-prune ----
  // xor1/xor2 exchanges via DPP quad_perm (VALU pipe); xor4/8 via bpermute.
  const int S = cnt < 32 ? cnt : 32;
  const int sbase = g4 << 5;
  u64 v0 = (sub < S) ? sb[sbase + sub] : ~0ull;
  u64 v1 = (16 + sub < S) ? sb[sbase + 16 + sub] : ~0ull;
  #pragma unroll
  for (int k = 2; k <= 16; k <<= 1) {
    #pragma unroll
    for (int j = k >> 1; j > 0; j >>= 1) {
      const u64 o0 = exch(v0, j);
      const u64 o1 = exch(v1, j);
      const bool up = ((sub & k) == 0);
      const bool j0 = ((sub & j) == 0);
      const bool km0 = (j0 == up);
      const bool km1 = (j0 != up);
      v0 = ((v0 < o0) == km0) ? v0 : o0;
      v1 = ((v1 < o1) == km1) ? v1 : o1;
    }
  }
  const u64 v = (v0 < v1) ? v0 : v1;         // exact top-16 set

  // ---- gather X (one neighbor per lane), DPP-reduce 9 moments over 16 lanes ----
  const int idx = (int)(u32)v & 0xFFF;
  const float* Xp = X + ((size_t)bb * NM + idx) * 3;
  const float x = Xp[0], y = Xp[1], z = Xp[2];
  const float sX = rorSum16F(x);
  const float sY = rorSum16F(y);
  const float sZ = rorSum16F(z);
  const float sXX = rorSum16F(x * x);
  const float sXY = rorSum16F(x * y);
  const float sXZ = rorSum16F(x * z);
  const float sYY = rorSum16F(y * y);
  const float sYZ = rorSum16F(y * z);
  const float sZZ = rorSum16F(z * z);

  // ---- covariance + closed-form symmetric 3x3 eigenvalues ----
  const float mx = sX * 0.0625f, my = sY * 0.0625f, mz = sZ * 0.0625f;
  const float c00 = sXX - 16.f * mx * mx;
  const float c11 = sYY - 16.f * my * my;
  const float c22 = sZZ - 16.f * mz * mz;
  const float c01 = sXY - 16.f * mx * my;
  const float c02 = sXZ - 16.f * mx * mz;
  const float c12 = sYZ - 16.f * my * mz;

  const float tr = c00 + c11 + c22;
  const float q3 = tr * (1.f / 3.f);
  const float b0 = c00 - q3, b1 = c11 - q3, b2 = c22 - q3;
  const float p2 = b0 * b0 + b1 * b1 + b2 * b2 +
                   2.f * (c01 * c01 + c02 * c02 + c12 * c12);
  float e0, e1, e2;
  if (p2 < 1e-30f) {
    e0 = e1 = e2 = q3;
  } else {
    const float p  = sqrtf(p2 * (1.f / 6.f));
    const float ip = 1.f / p;
    const float m00 = b0 * ip, m11 = b1 * ip, m22 = b2 * ip;
    const float m01 = c01 * ip, m02 = c02 * ip, m12 = c12 * ip;
    const float det = m00 * (m11 * m22 - m12 * m12)
                    - m01 * (m01 * m22 - m12 * m02)
                    + m02 * (m01 * m12 - m11 * m02);
    float r = 0.5f * det;
    r = fminf(1.f, fmaxf(-1.f, r));
    const float phi = acosf(r) * (1.f / 3.f);
    float sphi, cphi;
    __sincosf(phi, &sphi, &cphi);
    e0 = q3 + 2.f * p * cphi;                                        // largest
    e2 = q3 + 2.f * p * (-0.5f * cphi - 0.8660254037844386f * sphi); // smallest
    e1 = tr - e0 - e2;
  }

  if (sub == 0) {
    float* op = out + ((size_t)bb * NM + oq) * 3;
    op[0] = e0; op[1] = e1; op[2] = e2;
  }
}

extern "C" void kernel_launch(void* const* d_in, const int* in_sizes, int n_in,
                              void* d_out, int out_size, void* d_ws, size_t ws_size,
                              hipStream_t stream) {
  const float* X  = (const float*)d_in[0];
  const float* uv = (const float*)d_in[1];
  float* out = (float*)d_out;
  char* ws = (char*)d_ws;
  float4* uvS = (float4*)(ws + WS_UVS);
  u32*    csP = (u32*)(ws + WS_CS);

  bin_pts<<<dim3(NB), dim3(1024), 0, stream>>>(uv, uvS, csP);
  knn_eig<<<dim3(NB * NM / QPB), dim3(BLK), 0, stream>>>(X, uvS, csP, out);
}

// Round 13
// 24.384 us; speedup vs baseline: 1.1219x; 1.1219x over previous
//
#include <hip/hip_runtime.h>
#include <math.h>

typedef unsigned long long u64;
typedef unsigned int u32;

constexpr int NB  = 8;
constexpr int NM  = 4096;
constexpr int KNN = 16;
constexpr int WPB = 8;             // waves per block; 4 queries per wave
constexpr int QPW = 4;
constexpr int QPB = WPB * QPW;     // 32 queries per block
constexpr int BLK = WPB * 64;      // 512 threads
constexpr int GC  = 32;            // 32x32 grid, ~4 pts/cell
constexpr int NC  = GC * GC;
constexpr int CSST = NC + 1;
constexpr int SLG = 10;            // slots/lane: 160 group cap, 640 wave cap

// d_ws layout (fully rewritten every call -> poison-safe):
//   uvS float4[NB][NM] @ 0       (512 KB) cell-ordered (u, v, origidx_bits, 0)
//   cs  u32  [NB][CSST] @ 524288 ( 33 KB) cell start offsets
constexpr size_t WS_UVS = 0;
constexpr size_t WS_CS  = (size_t)NB * NM * 16;

__device__ __forceinline__ u64 shflx64(u64 v, int m) {
  unsigned lo = (unsigned)v, hi = (unsigned)(v >> 32);
  lo = __shfl_xor(lo, m, 64);
  hi = __shfl_xor(hi, m, 64);
  return ((u64)hi << 32) | lo;
}
__device__ __forceinline__ int rfl(int x) { return __builtin_amdgcn_readfirstlane(x); }
__device__ __forceinline__ int lanes_below(u64 m) {
  return (int)__builtin_amdgcn_mbcnt_hi((u32)(m >> 32),
             __builtin_amdgcn_mbcnt_lo((u32)m, 0u));
}
__device__ __forceinline__ u32 gm16(u64 m, int lane) {   // own 16-group's ballot bits
  return (u32)(m >> ((lane >> 4) << 4)) & 0xFFFFu;
}

// ---- DPP helpers (VALU pipe, no LDS). row_ror ctrls verified (R9-R11 passed). ----
template<int CTRL>
__device__ __forceinline__ int dppAddI(int v) {
  return v + __builtin_amdgcn_update_dpp(0, v, CTRL, 0xF, 0xF, false);
}
template<int CTRL>
__device__ __forceinline__ float dppAddF(float v) {
  int r = __builtin_amdgcn_update_dpp(0, __float_as_int(v), CTRL, 0xF, 0xF, false);
  return v + __int_as_float(r);
}
__device__ __forceinline__ int rorSum16I(int c) {      // all 16 lanes get group sum
  c = dppAddI<0x128>(c); c = dppAddI<0x124>(c);
  c = dppAddI<0x122>(c); c = dppAddI<0x121>(c);
  return c;
}
__device__ __forceinline__ float rorSum16F(float v) {
  v = dppAddF<0x128>(v); v = dppAddF<0x124>(v);
  v = dppAddF<0x122>(v); v = dppAddF<0x121>(v);
  return v;
}
// quad_perm exchanges: 0xB1 = [1,0,3,2] (xor1), 0x4E = [2,3,0,1] (xor2)
template<int CTRL>
__device__ __forceinline__ u64 dppSwap64(u64 v) {
  int lo = __builtin_amdgcn_update_dpp(0, (int)(u32)v,        CTRL, 0xF, 0xF, false);
  int hi = __builtin_amdgcn_update_dpp(0, (int)(u32)(v >> 32), CTRL, 0xF, 0xF, false);
  return ((u64)(u32)hi << 32) | (u32)lo;
}
__device__ __forceinline__ u64 exch(u64 v, int j) {    // j is compile-time (unrolled)
  if (j == 1) return dppSwap64<0xB1>(v);
  if (j == 2) return dppSwap64<0x4E>(v);
  return shflx64(v, j);
}

// ---------------- binning: counting-sort each batch's uv into 32x32 cells ----
__global__ __launch_bounds__(1024)
void bin_pts(const float* __restrict__ uv, float4* __restrict__ uvS,
             u32* __restrict__ cs) {
  __shared__ u32 cnt[NC];
  __shared__ u32 offs[NC];
  __shared__ u32 wtot[16];
  const int bb  = blockIdx.x;
  const int tid = threadIdx.x;           // 1024 threads == NC

  cnt[tid] = 0;
  __syncthreads();

  float2 c4[4];
  int cell[4];
  #pragma unroll
  for (int i = 0; i < 4; ++i) {
    const int p = tid + i * 1024;
    const float2 c = ((const float2*)(uv + (size_t)bb * NM * 2))[p];
    int cx = (int)(c.x * 32.f); cx = cx > GC - 1 ? GC - 1 : (cx < 0 ? 0 : cx);
    int cy = (int)(c.y * 32.f); cy = cy > GC - 1 ? GC - 1 : (cy < 0 ? 0 : cy);
    c4[i] = c; cell[i] = cy * GC + cx;
    atomicAdd(&cnt[cell[i]], 1u);
  }
  __syncthreads();

  {
    const int lane = tid & 63;
    u32 inc = cnt[tid];
    #pragma unroll
    for (int o = 1; o < 64; o <<= 1) {
      const u32 t = __shfl_up(inc, o, 64);
      if (lane >= o) inc += t;
    }
    offs[tid] = inc;                      // wave-inclusive
    if (lane == 63) wtot[tid >> 6] = inc;
  }
  __syncthreads();
  if (tid < 16) {
    u32 v = wtot[tid];
    #pragma unroll
    for (int o = 1; o < 16; o <<= 1) {
      const u32 t = __shfl_up(v, o, 64);
      if (tid >= o) v += t;
    }
    wtot[tid] = v;
  }
  __syncthreads();
  {
    const int w = tid >> 6;
    const u32 base = w ? wtot[w - 1] : 0u;
    const u32 excl = base + offs[tid] - cnt[tid];
    cs[bb * CSST + tid] = excl;
    offs[tid] = excl;
    if (tid == 0) cs[bb * CSST + NC] = NM;
  }
  __syncthreads();

  #pragma unroll
  for (int i = 0; i < 4; ++i) {
    const int p = tid + i * 1024;
    const u32 pos = atomicAdd(&offs[cell[i]], 1u);
    uvS[(size_t)bb * NM + pos] =
        make_float4(c4[i].x, c4[i].y, __uint_as_float((u32)p), 0.f);
  }
}

// ---------------- main: 4 queries/wave, straight-line batched loads ----
__global__ __launch_bounds__(BLK)
void knn_eig(const float* __restrict__ X, const float4* __restrict__ uvS,
             const u32* __restrict__ cs, float* __restrict__ out) {
  __shared__ u64 surv[WPB][QPW * 32];        // 8 KB: 32 slots per query

  const int tid  = threadIdx.x;
  const int lane = tid & 63;
  const int sub  = lane & 15;
  const int g4   = lane >> 4;
  const int wv   = tid >> 6;
  const int bb   = blockIdx.x >> 7;          // 128 blocks per batch
  const int s    = ((blockIdx.x & 127) << 5) + (wv << 2) + g4;  // sorted slot

  const float4* uvb = uvS + (size_t)bb * NM;
  const u32* csb = cs + bb * CSST;

  const float4 qc = uvb[s];                  // query in cell-sorted order
  const float qu = qc.x, qv = qc.y;
  const u32 oq = __float_as_uint(qc.z);      // original query index
  int cxv = (int)(qu * 32.f); cxv = cxv > GC - 1 ? GC - 1 : (cxv < 0 ? 0 : cxv);
  int cyv = (int)(qv * 32.f); cyv = cyv > GC - 1 ? GC - 1 : (cyv < 0 ? 0 : cyv);
  const int sx = (qu * 32.f - (float)cxv >= 0.5f) ? 1 : 0;
  const int sy = (qv * 32.f - (float)cyv >= 0.5f) ? 1 : 0;

  float d[SLG];
  u32   o[SLG];
  #pragma unroll
  for (int t = 0; t < SLG; ++t) d[t] = 1e30f;

  constexpr float TAU1 = 0.0017f;            // ~22 expected survivors
  constexpr float TAU2 = 0.002197265625f;    // (1.5/32)^2: 4x4 covered radius
  constexpr float TAU3 = 0.006103515625f;    // (2.5/32)^2: 6x6 covered radius
  constexpr float TAU4 = 0.019775390625f;    // (4.5/32)^2: 10x10 covered radius

  int cnt = 0;

  // ---- warm: 4x4 quadrant window, straight-line, batched independent loads ----
  {
    const int x0 = min(max(cxv - 2 + sx, 0), GC - 4);
    const int y0 = min(max(cyv - 2 + sy, 0), GC - 4);
    const int b = y0 * GC + x0;
    const int rs0 = (int)csb[b];          const int rc0 = (int)csb[b + 4] - rs0;
    const int rs1 = (int)csb[b + GC];     const int rc1 = rc0 + (int)csb[b + GC + 4] - rs1;
    const int rs2 = (int)csb[b + 2*GC];   const int rc2 = rc1 + (int)csb[b + 2*GC + 4] - rs2;
    const int rs3 = (int)csb[b + 3*GC];   const int total = rc2 + (int)csb[b + 3*GC + 4] - rs3;
    float4 cv[SLG];
    #pragma unroll
    for (int t = 0; t < SLG; ++t) {
      const int L = t * 16 + sub;
      int addr = rs0 + L;
      addr = (L >= rc0) ? rs1 + (L - rc0) : addr;
      addr = (L >= rc1) ? rs2 + (L - rc1) : addr;
      addr = (L >= rc2) ? rs3 + (L - rc2) : addr;
      addr = (L < total) ? addr : s;           // safe dummy: own query slot
      cv[t] = uvb[addr];                       // independent -> compiler batches
    }
    int cl = 0;
    #pragma unroll
    for (int t = 0; t < SLG; ++t) {
      const int L = t * 16 + sub;
      float dd = 1e30f;
      if (L < total) {
        const float dx = __fsub_rn(qu, cv[t].x);
        const float dy = __fsub_rn(qv, cv[t].y);
        dd = __fadd_rn(__fmul_rn(dx, dx), __fmul_rn(dy, dy));
      }
      d[t] = dd;
      o[t] = __float_as_uint(cv[t].z);
      cl += (dd <= TAU1) ? 1 : 0;
    }
    cnt = rorSum16I(cl);
  }

  // ---- ladder: tau1 -> tau2 (straight-line recount, register-only) ----
  float hi2 = TAU1, lo = 0.f;
  if (__any(cnt < KNN)) {
    int cl = 0;
    #pragma unroll
    for (int t = 0; t < SLG; ++t) cl += (d[t] <= TAU2) ? 1 : 0;
    const int c2 = rorSum16I(cl);
    if (cnt < KNN) { lo = TAU1; hi2 = TAU2; cnt = c2; }
  }

  // ---- cold1: 6x6 window refill for needy groups (predicated, no breaks) ----
  if (__any(cnt < KNN)) {
    const bool need = cnt < KNN;               // group-uniform
    int rs0 = 0, rs1 = 0, rs2 = 0, rs3 = 0, rs4 = 0, rs5 = 0;
    int rc0 = 0, rc1 = 0, rc2 = 0, rc3 = 0, rc4 = 0, total2 = 0;
    if (need) {
      const int x0 = min(max(cxv - 3 + sx, 0), GC - 6);
      const int y0 = min(max(cyv - 3 + sy, 0), GC - 6);
      const int b = y0 * GC + x0;
      rs0 = (int)csb[b];          rc0 = (int)csb[b + 6] - rs0;
      rs1 = (int)csb[b + GC];     rc1 = rc0 + (int)csb[b + GC + 6] - rs1;
      rs2 = (int)csb[b + 2*GC];   rc2 = rc1 + (int)csb[b + 2*GC + 6] - rs2;
      rs3 = (int)csb[b + 3*GC];   rc3 = rc2 + (int)csb[b + 3*GC + 6] - rs3;
      rs4 = (int)csb[b + 4*GC];   rc4 = rc3 + (int)csb[b + 4*GC + 6] - rs4;
      rs5 = (int)csb[b + 5*GC];   total2 = rc4 + (int)csb[b + 5*GC + 6] - rs5;
    }
    // 6x6 window is a superset of 4x4 -> total2 >= total; slots L >= total2
    // retain warm values (1e30f there), so stale entries never selected.
    int cl = 0;
    #pragma unroll
    for (int t = 0; t < SLG; ++t) {
      const int L = t * 16 + sub;
      float dd = 1e30f;
      u32 oid = 0;
      if (need && L < total2) {
        int addr = rs0 + L;
        addr = (L >= rc0) ? rs1 + (L - rc0) : addr;
        addr = (L >= rc1) ? rs2 + (L - rc1) : addr;
        addr = (L >= rc2) ? rs3 + (L - rc2) : addr;
        addr = (L >= rc3) ? rs4 + (L - rc3) : addr;
        addr = (L >= rc4) ? rs5 + (L - rc4) : addr;
        const float4 c = uvb[addr];
        const float dx = __fsub_rn(qu, c.x);
        const float dy = __fsub_rn(qv, c.y);
        dd = __fadd_rn(__fmul_rn(dx, dx), __fmul_rn(dy, dy));
        oid = __float_as_uint(c.z);
        d[t] = dd;
        o[t] = oid;
      }
      cl += (need && dd <= TAU3) ? 1 : 0;
    }
    const int c3 = rorSum16I(cl);
    if (need) { cnt = c3; lo = TAU2; hi2 = TAU3; }
  }

  // ---- narrow threshold until survivors fit 32/query (register-only) ----
  for (int it = 0; __any(cnt > 32) && it < 40; ++it) {
    const float mid = 0.5f * (lo + hi2);
    int cl = 0;
    #pragma unroll
    for (int t = 0; t < SLG; ++t) cl += ((cnt > 32) && (d[t] <= mid)) ? 1 : 0;
    const int c = rorSum16I(cl);
    if (cnt > 32) {
      if (!(mid > lo && mid < hi2)) cnt = 32;
      else if (c >= KNN) { hi2 = mid; cnt = c; }
      else lo = mid;
    }
  }

  // ---- compact survivors (register-only; oid from o[t]) ----
  u64* sb = surv[wv];
  {
    int base = 0;
    #pragma unroll
    for (int t = 0; t < SLG; ++t) {
      const bool p = d[t] <= hi2;
      const u32 mg = gm16(__ballot(p), lane);
      if (p) {
        const int pos = base + (int)__popc(mg & ((1u << sub) - 1u));
        if (pos < 32)
          sb[(g4 << 5) + pos] = ((u64)__float_as_uint(d[t]) << 32) | (u64)o[t];
      }
      base += (int)__popc(mg);
    }
  }

  // ---- cold2: 10x10 window, full-wave serialized (corners, rare) ----
  if (__any(cnt < KNN)) {
    #pragma unroll 1
    for (int g = 0; g < QPW; ++g) {
      if (!rfl((__shfl(cnt, g << 4, 64) < KNN) ? 1 : 0)) continue;
      const float gu = __shfl(qu, g << 4, 64);
      const float gv = __shfl(qv, g << 4, 64);
      int gcx = (int)(gu * 32.f); gcx = min(max(gcx, 0), GC - 1);
      int gcy = (int)(gv * 32.f); gcy = min(max(gcy, 0), GC - 1);
      const int gsx = (gu * 32.f - (float)gcx >= 0.5f) ? 1 : 0;
      const int gsy = (gv * 32.f - (float)gcy >= 0.5f) ? 1 : 0;
      const int x0 = min(max(gcx - 5 + gsx, 0), GC - 10);
      const int y0 = min(max(gcy - 5 + gsy, 0), GC - 10);
      int rstart[10], rcum[10];
      int cum = 0;
      #pragma unroll
      for (int r = 0; r < 10; ++r) {
        const int b = (y0 + r) * GC + x0;
        rstart[r] = (int)csb[b];
        cum += (int)csb[b + 10] - rstart[r];
        rcum[r] = cum;
      }
      const int gtotal = cum;
      const int gts = rfl(min((gtotal + 63) >> 6, SLG));
      float ghi = TAU4, glo = TAU3;
      int gcnt = 0;
      #pragma unroll
      for (int t = 0; t < SLG; ++t) {
        if (t >= gts) break;
        const int L = t * 64 + lane;
        int addr = rstart[0] + L;
        #pragma unroll
        for (int r = 1; r < 10; ++r)
          addr = (L >= rcum[r - 1]) ? rstart[r] + (L - rcum[r - 1]) : addr;
        float dd = 1e30f;
        u32 oid = 0;
        if (L < gtotal) {
          const float4 c = uvb[addr];
          const float dx = __fsub_rn(gu, c.x);
          const float dy = __fsub_rn(gv, c.y);
          dd = __fadd_rn(__fmul_rn(dx, dx), __fmul_rn(dy, dy));
          oid = __float_as_uint(c.z);
        }
        d[t] = dd; o[t] = oid;               // warm d/o dead after compaction
        gcnt += (int)__popcll(__ballot(dd <= ghi));
      }
      for (int it = 0; rfl(gcnt) > 32 && it < 40; ++it) {
        const float mid = 0.5f * (glo + ghi);
        if (!(mid > glo && mid < ghi)) break;
        int c = 0;
        #pragma unroll
        for (int t = 0; t < SLG; ++t) {
          if (t >= gts) break;
          c += (int)__popcll(__ballot(d[t] <= mid));
        }
        if (c >= KNN) { ghi = mid; gcnt = c; } else glo = mid;
      }
      int base = 0;
      #pragma unroll
      for (int t = 0; t < SLG; ++t) {
        if (t >= gts) break;
        const bool p = d[t] <= ghi;
        const u64 m = __ballot(p);
        if (p) {
          const int pos = base + lanes_below(m);
          if (pos < 32)
            sb[(g << 5) + pos] = ((u64)__float_as_uint(d[t]) << 32) | (u64)o[t];
        }
        base += (int)__popcll(m);
      }
      if (g4 == g) cnt = min(rfl(gcnt), 32);
    }
  }

  // ---- top-16 selection: sort v0 asc, v1 desc (parallel chains), min-prune ----
  const int S = cnt < 32 ? cnt : 32;
  const int sbase = g4 << 5;
  u64 v0 = (sub < S) ? sb[sbase + sub] : ~0ull;
  u64 v1 = (16 + sub < S) ? sb[sbase + 16 + sub] : ~0ull;
  #pragma unroll
  for (int k = 2; k <= 16; k <<= 1) {
    #pragma unroll
    for (int j = k >> 1; j > 0; j >>= 1) {
      const u64 o0 = exch(v0, j);
      const u64 o1 = exch(v1, j);
      const bool up = ((sub & k) == 0);
      const bool j0 = ((sub & j) == 0);
      const bool km0 = (j0 == up);
      const bool km1 = (j0 != up);
      v0 = ((v0 < o0) == km0) ? v0 : o0;
      v1 = ((v1 < o1) == km1) ? v1 : o1;
    }
  }
  const u64 v = (v0 < v1) ? v0 : v1;         // exact top-16 set

  // ---- gather X (one neighbor per lane), DPP-reduce 9 moments over 16 lanes ----
  const int idx = (int)(u32)v & 0xFFF;
  const float* Xp = X + ((size_t)bb * NM + idx) * 3;
  const float x = Xp[0], y = Xp[1], z = Xp[2];
  const float sX = rorSum16F(x);
  const float sY = rorSum16F(y);
  const float sZ = rorSum16F(z);
  const float sXX = rorSum16F(x * x);
  const float sXY = rorSum16F(x * y);
  const float sXZ = rorSum16F(x * z);
  const float sYY = rorSum16F(y * y);
  const float sYZ = rorSum16F(y * z);
  const float sZZ = rorSum16F(z * z);

  // ---- covariance + closed-form symmetric 3x3 eigenvalues ----
  const float mx = sX * 0.0625f, my = sY * 0.0625f, mz = sZ * 0.0625f;
  const float c00 = sXX - 16.f * mx * mx;
  const float c11 = sYY - 16.f * my * my;
  const float c22 = sZZ - 16.f * mz * mz;
  const float c01 = sXY - 16.f * mx * my;
  const float c02 = sXZ - 16.f * mx * mz;
  const float c12 = sYZ - 16.f * my * mz;

  const float tr = c00 + c11 + c22;
  const float q3 = tr * (1.f / 3.f);
  const float b0 = c00 - q3, b1 = c11 - q3, b2 = c22 - q3;
  const float p2 = b0 * b0 + b1 * b1 + b2 * b2 +
                   2.f * (c01 * c01 + c02 * c02 + c12 * c12);
  float e0, e1, e2;
  if (p2 < 1e-30f) {
    e0 = e1 = e2 = q3;
  } else {
    const float p  = sqrtf(p2 * (1.f / 6.f));
    const float ip = 1.f / p;
    const float m00 = b0 * ip, m11 = b1 * ip, m22 = b2 * ip;
    const float m01 = c01 * ip, m02 = c02 * ip, m12 = c12 * ip;
    const float det = m00 * (m11 * m22 - m12 * m12)
                    - m01 * (m01 * m22 - m12 * m02)
                    + m02 * (m01 * m12 - m11 * m02);
    float r = 0.5f * det;
    r = fminf(1.f, fmaxf(-1.f, r));
    const float phi = acosf(r) * (1.f / 3.f);
    float sphi, cphi;
    __sincosf(phi, &sphi, &cphi);
    e0 = q3 + 2.f * p * cphi;                                        // largest
    e2 = q3 + 2.f * p * (-0.5f * cphi - 0.8660254037844386f * sphi); // smallest
    e1 = tr - e0 - e2;
  }

  if (sub == 0) {
    float* op = out + ((size_t)bb * NM + oq) * 3;
    op[0] = e0; op[1] = e1; op[2] = e2;
  }
}

extern "C" void kernel_launch(void* const* d_in, const int* in_sizes, int n_in,
                              void* d_out, int out_size, void* d_ws, size_t ws_size,
                              hipStream_t stream) {
  const float* X  = (const float*)d_in[0];
  const float* uv = (const float*)d_in[1];
  float* out = (float*)d_out;
  char* ws = (char*)d_ws;
  float4* uvS = (float4*)(ws + WS_UVS);
  u32*    csP = (u32*)(ws + WS_CS);

  bin_pts<<<dim3(NB), dim3(1024), 0, stream>>>(uv, uvS, csP);
  knn_eig<<<dim3(NB * NM / QPB), dim3(BLK), 0, stream>>>(X, uvS, csP, out);
}